// Round 4
// baseline (375.655 us; speedup 1.0000x reference)
//
#include <hip/hip_runtime.h>
#include <hip/hip_bf16.h>

// Problem constants
#define B_   64
#define L_   1024
#define H_   512
#define T_   100
#define C_   97
#define TP_  112   // T padded to 7*16

typedef _Float16 h8 __attribute__((ext_vector_type(8)));   // 8 fp16 (4 VGPRs)
typedef __attribute__((ext_vector_type(4))) float f32x4;   // MFMA C/D

// ---------------------------------------------------------------------------
// k0: prep. pos_emb fp32 -> fp16 [112][512] (rows 100..111 zero);
//     W_gen fp32 -> fp16 [112][512] (rows 97..111 zero). Grid 224.
// ---------------------------------------------------------------------------
__global__ __launch_bounds__(256) void k0_prep(
    const float* __restrict__ emb, const float* __restrict__ W,
    _Float16* __restrict__ embh, _Float16* __restrict__ Wh) {
  const int row = blockIdx.x, tid = threadIdx.x;
  if (row < TP_) {
    for (int j = tid; j < H_; j += 256)
      embh[(size_t)row * H_ + j] =
          (row < T_) ? (_Float16)emb[(size_t)row * H_ + j] : (_Float16)0.f;
  } else {
    const int c = row - TP_;
    for (int j = tid; j < H_; j += 256)
      Wh[(size_t)c * H_ + j] =
          (c < C_) ? (_Float16)W[(size_t)c * H_ + j] : (_Float16)0.f;
  }
}

// ---------------------------------------------------------------------------
// K1: scores = fmap @ emb^T (f16 MFMA), stats per 64-row block, and
// TRANSPOSED store scT[b][t][l] = fp16(s - M_blk) via LDS tile.
// Grid 1024 (= B x 16 l-blocks of 64), block 256, wave = 16 rows x 112 t.
// ---------------------------------------------------------------------------
__global__ __launch_bounds__(256, 4) void k1_scores(
    const float* __restrict__ fmap, const _Float16* __restrict__ embh,
    _Float16* __restrict__ scT, float* __restrict__ part) {
  __shared__ float red_m[4 * TP_];
  __shared__ float red_s[4 * TP_];
  __shared__ float sMb[TP_];
  __shared__ _Float16 tile[TP_ * 72];     // [t][l_local], stride 72 (16B-aligned rows)
  const int tid = threadIdx.x;
  const int wave = tid >> 6, lane = tid & 63;
  const int quad = lane >> 4, cc = lane & 15;
  const int b = blockIdx.x >> 4;
  const int m0 = blockIdx.x * 64 + wave * 16;   // global l-row base for this wave

  f32x4 acc[7];
#pragma unroll
  for (int i = 0; i < 7; ++i) acc[i] = (f32x4){0.f, 0.f, 0.f, 0.f};

  const float* ap = fmap + (size_t)(m0 + cc) * H_ + quad * 8;
#pragma unroll 2
  for (int k = 0; k < H_; k += 32) {
    float4 x0 = *(const float4*)(ap + k);
    float4 x1 = *(const float4*)(ap + k + 4);
    h8 a;
    a[0] = (_Float16)x0.x; a[1] = (_Float16)x0.y;
    a[2] = (_Float16)x0.z; a[3] = (_Float16)x0.w;
    a[4] = (_Float16)x1.x; a[5] = (_Float16)x1.y;
    a[6] = (_Float16)x1.z; a[7] = (_Float16)x1.w;
#pragma unroll
    for (int i = 0; i < 7; ++i) {
      h8 bf = *(const h8*)(embh + (size_t)(i * 16 + cc) * H_ + k + quad * 8);
      acc[i] = __builtin_amdgcn_mfma_f32_16x16x32_f16(a, bf, acc[i], 0, 0, 0);
    }
  }

  // per-(t) partial stats over this wave's 16 rows (4 r-values x 4 quads)
  float pm[7], ps[7];
#pragma unroll
  for (int i = 0; i < 7; ++i) {
    float m = acc[i][0];
#pragma unroll
    for (int r = 1; r < 4; ++r) m = fmaxf(m, acc[i][r]);
    float s = 0.f;
#pragma unroll
    for (int r = 0; r < 4; ++r) s += __expf(acc[i][r] - m);
    pm[i] = m; ps[i] = s;
  }
#pragma unroll
  for (int d = 16; d < 64; d <<= 1) {     // reduce across quads (same t col)
#pragma unroll
    for (int i = 0; i < 7; ++i) {
      float om = __shfl_xor(pm[i], d, 64);
      float os = __shfl_xor(ps[i], d, 64);
      float M = fmaxf(pm[i], om);
      ps[i] = ps[i] * __expf(pm[i] - M) + os * __expf(om - M);
      pm[i] = M;
    }
  }
  if (lane < 16) {
#pragma unroll
    for (int i = 0; i < 7; ++i) {
      red_m[wave * TP_ + i * 16 + lane] = pm[i];
      red_s[wave * TP_ + i * 16 + lane] = ps[i];
    }
  }
  __syncthreads();
  if (tid < TP_) {
    float M = red_m[tid], S = red_s[tid];
#pragma unroll
    for (int w = 1; w < 4; ++w) {
      float om = red_m[w * TP_ + tid], os = red_s[w * TP_ + tid];
      float nM = fmaxf(M, om);
      S = S * __expf(M - nM) + os * __expf(om - nM);
      M = nM;
    }
    float* p = part + ((size_t)blockIdx.x * TP_ + tid) * 2;
    p[0] = M; p[1] = S;
    sMb[tid] = M;
  }
  __syncthreads();
  // write acc into LDS transposed: tile[t][l_local]
#pragma unroll
  for (int i = 0; i < 7; ++i) {
    float mb = sMb[i * 16 + cc];
#pragma unroll
    for (int r = 0; r < 4; ++r)
      tile[(i * 16 + cc) * 72 + wave * 16 + quad * 4 + r] = (_Float16)(acc[i][r] - mb);
  }
  __syncthreads();
  // stream out coalesced: 112 t x 64 l = 896 h8 chunks
  _Float16* dst = scT + (size_t)b * TP_ * L_ + (size_t)(blockIdx.x & 15) * 64;
  for (int idx = tid; idx < 896; idx += 256) {
    const int t = idx >> 3, c = idx & 7;
    h8 v = *(const h8*)&tile[t * 72 + c * 8];
    *(h8*)(dst + (size_t)t * L_ + c * 8) = v;
  }
}

// ---------------------------------------------------------------------------
// K2: merge 16 per-block stats -> streaming softmax in [t][l] layout.
// attnT[b][t][l] = exp(scT + (M_blk[l/64] - M)) / S, fp16.
// Grid 512 (= B x 8 groups of 14 t-rows), block 256.
// ---------------------------------------------------------------------------
__global__ __launch_bounds__(256) void k2_softmax(
    const _Float16* __restrict__ scT, const float* __restrict__ part,
    _Float16* __restrict__ attnT) {
  __shared__ float sAdj[16 * 14];   // [lblk][t_local]
  __shared__ float sInv[14];
  const int b = blockIdx.x >> 3, tg = blockIdx.x & 7;
  const int tid = threadIdx.x;
  if (tid < 14) {
    const int t = tg * 14 + tid;
    float M = -1e30f, S = 0.f;
    for (int k = 0; k < 16; ++k) {
      const float* p = part + ((size_t)(b * 16 + k) * TP_ + t) * 2;
      float om = p[0], os = p[1];
      float nM = fmaxf(M, om);
      S = S * __expf(M - nM) + os * __expf(om - nM);
      M = nM;
    }
    sInv[tid] = 1.f / S;
    for (int k = 0; k < 16; ++k)
      sAdj[k * 14 + tid] = part[((size_t)(b * 16 + k) * TP_ + t) * 2] - M;
  }
  __syncthreads();
  const size_t base = ((size_t)b * TP_ + tg * 14) * L_;
  for (int idx = tid; idx < 14 * 128; idx += 256) {
    const int t = idx >> 7, c = idx & 127;   // 8 l's per chunk, within one 64-l block
    const size_t off = base + (size_t)t * L_ + c * 8;
    h8 v = *(const h8*)(scT + off);
    const float adj = sAdj[(c >> 3) * 14 + t];
    const float inv = sInv[t];
    h8 o;
#pragma unroll
    for (int j = 0; j < 8; ++j)
      o[j] = (_Float16)(__expf((float)v[j] + adj) * inv);
    *(h8*)(attnT + off) = o;
  }
}

// ---------------------------------------------------------------------------
// K3: ctx[b][t][h] = sum_l attnT[b][t][l] * origin[b][l][h]   (fp16 out)
// A = attnT (k-contig, 7x16B vector loads); B = origin natural fp32
// (8 scalar dwords/k-step, 64B-coalesced across lanes), cvt in-reg.
// No LDS, no barriers. Grid 512 (= B x 8 h-blocks of 64), block 256.
// ---------------------------------------------------------------------------
__global__ __launch_bounds__(256) void k3_context(
    const _Float16* __restrict__ attnT, const float* __restrict__ origin,
    _Float16* __restrict__ ctx) {
  const int b = blockIdx.x >> 3, hb = (blockIdx.x & 7) * 64;
  const int tid = threadIdx.x;
  const int wave = tid >> 6, lane = tid & 63;
  const int quad = lane >> 4, cc = lane & 15;

  f32x4 acc[7];
#pragma unroll
  for (int i = 0; i < 7; ++i) acc[i] = (f32x4){0.f, 0.f, 0.f, 0.f};

  const _Float16* aA = attnT + ((size_t)b * TP_ + cc) * L_ + quad * 8;
  const float* bp = origin + ((size_t)b * L_ + quad * 8) * H_ + hb + wave * 16 + cc;

#pragma unroll 2
  for (int l0 = 0; l0 < L_; l0 += 32) {
    h8 bfh;
#pragma unroll
    for (int j = 0; j < 8; ++j) bfh[j] = (_Float16)bp[(size_t)(l0 + j) * H_];
#pragma unroll
    for (int i = 0; i < 7; ++i) {
      h8 af = *(const h8*)(aA + (size_t)(i * 16) * L_ + l0);
      acc[i] = __builtin_amdgcn_mfma_f32_16x16x32_f16(af, bfh, acc[i], 0, 0, 0);
    }
  }
  const int h = hb + wave * 16 + cc;
#pragma unroll
  for (int i = 0; i < 7; ++i)
#pragma unroll
    for (int r = 0; r < 4; ++r)
      ctx[((size_t)b * TP_ + i * 16 + quad * 4 + r) * H_ + h] = (_Float16)acc[i][r];
}

// ---------------------------------------------------------------------------
// K4: out[b,t,c] = sum_h ctx[b][t][h] * W[c][h] + bias[c]   (fp32 out)
// Both operands k-contiguous fp16 -> pure 16B vector loads.
// Grid 448 (= B x 7 t-tiles), block 256. Wave w covers c-tiles {w, w+4}.
// ---------------------------------------------------------------------------
__global__ __launch_bounds__(256) void k4_out(
    const _Float16* __restrict__ ctx, const _Float16* __restrict__ Wh,
    const float* __restrict__ bias, float* __restrict__ out) {
  const int b = blockIdx.x / 7, mt = blockIdx.x % 7;
  const int tid = threadIdx.x;
  const int wave = tid >> 6, lane = tid & 63;
  const int quad = lane >> 4, cc = lane & 15;
  f32x4 acc0 = (f32x4){0.f, 0.f, 0.f, 0.f};
  f32x4 acc1 = (f32x4){0.f, 0.f, 0.f, 0.f};
  const int c0 = wave * 16 + cc;
  const int c1 = (wave + 4) * 16 + cc;          // <= 111 when hasB
  const bool hasB = (wave < 3);
  const _Float16* ap  = ctx + ((size_t)b * TP_ + mt * 16 + cc) * H_ + quad * 8;
  const _Float16* b0p = Wh + (size_t)c0 * H_ + quad * 8;
  const _Float16* b1p = Wh + (size_t)(hasB ? c1 : c0) * H_ + quad * 8;
#pragma unroll 2
  for (int k = 0; k < H_; k += 32) {
    h8 af = *(const h8*)(ap + k);
    h8 bf0 = *(const h8*)(b0p + k);
    acc0 = __builtin_amdgcn_mfma_f32_16x16x32_f16(af, bf0, acc0, 0, 0, 0);
    if (hasB) {
      h8 bf1 = *(const h8*)(b1p + k);
      acc1 = __builtin_amdgcn_mfma_f32_16x16x32_f16(af, bf1, acc1, 0, 0, 0);
    }
  }
  const float bias0 = (c0 < C_) ? bias[c0] : 0.f;
  const float bias1 = (hasB && c1 < C_) ? bias[c1] : 0.f;
#pragma unroll
  for (int r = 0; r < 4; ++r) {
    const int t = mt * 16 + quad * 4 + r;
    if (t < T_) {
      if (c0 < C_) out[((size_t)b * T_ + t) * C_ + c0] = acc0[r] + bias0;
      if (hasB && c1 < C_) out[((size_t)b * T_ + t) * C_ + c1] = acc1[r] + bias1;
    }
  }
}

// ---------------------------------------------------------------------------
extern "C" void kernel_launch(void* const* d_in, const int* in_sizes, int n_in,
                              void* d_out, int out_size, void* d_ws, size_t ws_size,
                              hipStream_t stream) {
  const float* fmap   = (const float*)d_in[0];  // [B,L,H] fp32
  const float* origin = (const float*)d_in[1];  // [B,L,H] fp32
  const float* emb    = (const float*)d_in[2];  // [T,H]   fp32
  const float* W      = (const float*)d_in[3];  // [C,H]   fp32
  const float* bias   = (const float*)d_in[4];  // [C]     fp32
  float* out = (float*)d_out;                   // [B,T,C] fp32

  char* ws = (char*)d_ws;
  // embh  f16 [112][512]       :    114,688 B @ 0
  // Wh    f16 [112][512]       :    114,688 B @ 114,688
  // scT   f16 [64][112][1024]  : 14,680,064 B @ 229,376
  // part  f32 [1024][112][2]   :    917,504 B @ 14,909,440
  // attnT f16 [64][112][1024]  : 14,680,064 B @ 15,826,944
  // ctx   f16 [64][112][512]   :  7,340,032 B @ 30,507,008   (end 37.8 MB)
  _Float16* embh  = (_Float16*)(ws);
  _Float16* Wh    = (_Float16*)(ws + 114688);
  _Float16* scT   = (_Float16*)(ws + 229376);
  float*    part  = (float*)   (ws + 14909440);
  _Float16* attnT = (_Float16*)(ws + 15826944);
  _Float16* ctx   = (_Float16*)(ws + 30507008);

  hipLaunchKernelGGL(k0_prep,    dim3(224),  dim3(256), 0, stream, emb, W, embh, Wh);
  hipLaunchKernelGGL(k1_scores,  dim3(1024), dim3(256), 0, stream, fmap, embh, scT, part);
  hipLaunchKernelGGL(k2_softmax, dim3(512),  dim3(256), 0, stream, scT, part, attnT);
  hipLaunchKernelGGL(k3_context, dim3(512),  dim3(256), 0, stream, attnT, origin, ctx);
  hipLaunchKernelGGL(k4_out,     dim3(448),  dim3(256), 0, stream, ctx, Wh, bias, out);
}